// Round 9
// baseline (699.589 us; speedup 1.0000x reference)
//
#include <hip/hip_runtime.h>
#include <hip/hip_bf16.h>
#include <math.h>

typedef __bf16 bf16_t;
typedef __bf16 bf16x4 __attribute__((ext_vector_type(4)));
typedef __bf16 bf16x8 __attribute__((ext_vector_type(8)));
typedef float f32x4 __attribute__((ext_vector_type(4)));
typedef float f32x2 __attribute__((ext_vector_type(2)));

static constexpr int N_NODES = 32768;
static constexpr int N_EDGES = N_NODES * 16;

#define GLB_PTR(p) ((const __attribute__((address_space(1))) void*)(p))
#define LDS_PTR(p) ((__attribute__((address_space(3))) void*)(p))

// flag per tensor: 0 = fp32, 1 = bf16, 2 = all-zero (return 0 without reading)
__device__ __forceinline__ float load_ext(const void* p, long i, int fl) {
  if (fl == 2) return 0.f;
  return fl ? (float)((const bf16_t*)p)[i] : ((const float*)p)[i];
}

// Per-block self-sniff from a fixed 64-pair sample (uniform across threads).
__device__ __forceinline__ int sniff_float_dev(const void* p) {  // 0=fp32, 1=bf16
  const unsigned short* u = (const unsigned short*)p;
  int sane = 0;
#pragma unroll 8
  for (int i = 0; i < 64; ++i) {
    unsigned short we = u[2 * i];
    int e = (we >> 7) & 0xFF;
    if (we != 0 && e >= 100 && e <= 140) sane++;
  }
  return sane > 32;
}
__device__ __forceinline__ int sniff_int64_dev(const void* p) {  // 1=int64
  const int* ip = (const int*)p;
  int z = 0;
#pragma unroll 8
  for (int i = 0; i < 64; ++i)
    if (ip[2 * i + 1] == 0) z++;
  return z > 48;
}
__device__ __forceinline__ int edge_at(const void* ei, long i, int fl64) {
  return fl64 ? (int)((const long long*)ei)[i] : ((const int*)ei)[i];
}

// ---------------------------------------------------------------------------
// prep1: blocks 0..19 sniff tensor dtypes into flags; blocks 20..51 zero deg.
// ---------------------------------------------------------------------------
struct SniffArgs {
  const void* ptr[20];
  int elems[20];
  int kind[20];
};

__global__ __launch_bounds__(256) void prep1(SniffArgs a, int* flags, int* deg) {
  int b = blockIdx.x;
  int t = threadIdx.x;
  if (b >= 20) {
    int i = (b - 20) * 1024 + t * 4;
    *(int4*)(deg + i) = int4{0, 0, 0, 0};
    return;
  }
  __shared__ int s1[256], s2[256];
  if (a.kind[b] == 0) {
    const unsigned short* p = (const unsigned short*)a.ptr[b];
    int pairs = min(1024, a.elems[b] / 2);
    int sane = 0, nz = 0;
    for (int i = t; i < pairs; i += 256) {
      unsigned short we = p[2 * i], wo = p[2 * i + 1];
      if (we | wo) nz++;
      int e = (we >> 7) & 0xFF;
      if (we != 0 && e >= 100 && e <= 140) sane++;
    }
    s1[t] = sane; s2[t] = nz;
    __syncthreads();
    for (int o = 128; o >= 1; o >>= 1) {
      if (t < o) { s1[t] += s1[t + o]; s2[t] += s2[t + o]; }
      __syncthreads();
    }
    if (t == 0)
      flags[b] = (s2[0] == 0) ? 2 : ((2 * s1[0] > pairs) ? 1 : 0);
  } else {
    const int* ip = (const int*)a.ptr[b];
    int n = min(512, a.elems[b] / 2);
    int zeros = 0;
    for (int i = t; i < n; i += 256)
      if (ip[2 * i + 1] == 0) zeros++;
    s1[t] = zeros;
    __syncthreads();
    for (int o = 128; o >= 1; o >>= 1) {
      if (t < o) s1[t] += s1[t + o];
      __syncthreads();
    }
    if (t == 0) flags[b] = (s1[0] * 4 > n * 3) ? 1 : 0;
  }
}

// ---------------------------------------------------------------------------
// prep2: [0,8192) convert x -> bf16 | [8192,9792) weight transpose |
// [9792,11840) degree count. All parts self-sniff their tensor dtype.
// ---------------------------------------------------------------------------
struct TransDesc { const void* src; long soff; bf16_t* dst; int K; int N; int tile0; };
struct Prep2Args {
  TransDesc d[13];
  const void* x;
  const void* ei;
  bf16_t* xb;
  int* deg;
};

__global__ __launch_bounds__(256) void prep2(Prep2Args a) {
  int b = blockIdx.x;
  int t = threadIdx.x;
  if (b < 8192) {
    int fl = sniff_float_dev(a.x);
    int i = b * 1024 + t * 4;
    if (fl) {
      *(int2*)(a.xb + i) = *(const int2*)((const bf16_t*)a.x + i);
    } else {
      float4 v = *(const float4*)((const float*)a.x + i);
      a.xb[i] = (bf16_t)v.x; a.xb[i + 1] = (bf16_t)v.y;
      a.xb[i + 2] = (bf16_t)v.z; a.xb[i + 3] = (bf16_t)v.w;
    }
  } else if (b < 9792) {
    __shared__ bf16_t tile[32][33];
    int blk = b - 8192;
    int i = 0;
#pragma unroll
    for (int j = 1; j < 13; ++j)
      if (blk >= a.d[j].tile0) i = j;
    TransDesc dd = a.d[i];
    int fl = sniff_float_dev(dd.src);
    int tt = blk - dd.tile0;
    int tiles_x = dd.N / 32;
    int nbase = (tt % tiles_x) * 32;
    int kbase = (tt / tiles_x) * 32;
    int tx = t & 31, ty = t >> 5;
#pragma unroll
    for (int j = 0; j < 32; j += 8)
      tile[ty + j][tx] = (bf16_t)load_ext(dd.src, dd.soff + (long)(kbase + ty + j) * dd.N + nbase + tx, fl);
    __syncthreads();
#pragma unroll
    for (int j = 0; j < 32; j += 8)
      dd.dst[(size_t)(nbase + ty + j) * dd.K + kbase + tx] = tile[tx][ty + j];
  } else {
    int fl = sniff_int64_dev(a.ei);
    int e = (b - 9792) * 256 + t;
    atomicAdd(&a.deg[edge_at(a.ei, (long)N_EDGES + e, fl)], 1);
  }
}

// ---------------------------------------------------------------------------
// scan: exclusive prefix over deg -> off[0..N]; also seeds cursor = prefix.
// ---------------------------------------------------------------------------
__global__ __launch_bounds__(1024) void scan_offsets(const int* __restrict__ deg,
                                                     int* __restrict__ off,
                                                     int* __restrict__ cursor) {
  __shared__ int s[1024];
  int t = threadIdx.x;
  int base = t * 32;
  int sum = 0;
  for (int i = 0; i < 32; ++i) sum += deg[base + i];
  s[t] = sum;
  __syncthreads();
  for (int o = 1; o < 1024; o <<= 1) {
    int v = (t >= o) ? s[t - o] : 0;
    __syncthreads();
    s[t] += v;
    __syncthreads();
  }
  int run = s[t] - sum;
  for (int i = 0; i < 32; ++i) {
    off[base + i] = run;
    cursor[base + i] = run;
    run += deg[base + i];
  }
  if (t == 1023) off[N_NODES] = run;
}

__global__ __launch_bounds__(256) void scatter_edges(const void* __restrict__ ei,
                                                     const int* __restrict__ cursor_unused,
                                                     int* __restrict__ cursor,
                                                     int* __restrict__ csr) {
  int fl = sniff_int64_dev(ei);
  int e = blockIdx.x * 256 + threadIdx.x;
  int d = edge_at(ei, (long)N_EDGES + e, fl);
  int p = atomicAdd(&cursor[d], 1);
  csr[p] = edge_at(ei, e, fl);
}

// ---------------------------------------------------------------------------
// Attention v5: fp8 q/k/v, one wave per node, 4-deep prefetch, packed cvt.
// deg>0 derived from off (no deg array). Lane covers 4 dims at lane*4.
// ---------------------------------------------------------------------------
__global__ __launch_bounds__(256) void attn_k(const unsigned char* __restrict__ qkv8,
                                              const int* __restrict__ off,
                                              const int* __restrict__ csr,
                                              bf16_t* __restrict__ agg) {
  const int nid = blockIdx.x * 4 + (threadIdx.x >> 6);
  const int lane = threadIdx.x & 63;
  const unsigned char* nb = qkv8 + (size_t)nid * 768;
  unsigned qw = *(const unsigned*)(nb + lane * 4);
  f32x2 q01 = __builtin_amdgcn_cvt_pk_f32_fp8(qw, false);
  f32x2 q23 = __builtin_amdgcn_cvt_pk_f32_fp8(qw, true);

  const int e0 = off[nid], e1 = off[nid + 1];
  const int ne = e1 - e0 + 1;  // + self edge (last)
  int sl = (lane < ne - 1) ? csr[e0 + lane] : nid;  // neighbor list in regs

  unsigned kb[4], vb[4];
#pragma unroll
  for (int j = 0; j < 4; ++j) {
    if (j < ne) {
      int s = (j == ne - 1) ? nid : __shfl(sl, j);
      const unsigned char* row = qkv8 + (size_t)s * 768 + lane * 4;
      kb[j] = *(const unsigned*)(row + 256);
      vb[j] = *(const unsigned*)(row + 512);
    }
  }

  float l = 0.f, a0 = 0.f, a1 = 0.f, a2 = 0.f, a3 = 0.f;
  for (int idx = 0; idx < ne; ++idx) {
    unsigned kr = kb[idx & 3], vr = vb[idx & 3];
    int pj = idx + 4;
    if (pj < ne) {
      int s = (pj == ne - 1) ? nid : (pj < 64 ? __shfl(sl, pj) : csr[e0 + pj]);
      const unsigned char* row = qkv8 + (size_t)s * 768 + lane * 4;
      kb[idx & 3] = *(const unsigned*)(row + 256);
      vb[idx & 3] = *(const unsigned*)(row + 512);
    }
    f32x2 k01 = __builtin_amdgcn_cvt_pk_f32_fp8(kr, false);
    f32x2 k23 = __builtin_amdgcn_cvt_pk_f32_fp8(kr, true);
    float p = q01[0] * k01[0] + q01[1] * k01[1] + q23[0] * k23[0] + q23[1] * k23[1];
    p += __shfl_xor(p, 1);
    p += __shfl_xor(p, 2);
    p += __shfl_xor(p, 4);
    float ev = __expf(fminf(p * 0.17677669529663687f, 60.f));
    f32x2 v01 = __builtin_amdgcn_cvt_pk_f32_fp8(vr, false);
    f32x2 v23 = __builtin_amdgcn_cvt_pk_f32_fp8(vr, true);
    a0 += ev * v01[0];
    a1 += ev * v01[1];
    a2 += ev * v23[0];
    a3 += ev * v23[1];
    l += ev;
  }

  float inv = (e1 > e0) ? 1.f / l : 0.f;  // deg>0 <=> off[n+1]>off[n]
  bf16x4 ov;
  ov[0] = (bf16_t)(a0 * inv); ov[1] = (bf16_t)(a1 * inv);
  ov[2] = (bf16_t)(a2 * inv); ov[3] = (bf16_t)(a3 * inv);
  *(bf16x4*)(agg + (size_t)nid * 256 + lane * 4) = ov;
}

// ---------------------------------------------------------------------------
// MFMA GEMM (128x128 tile, BK=64, global_load_lds + XOR swizzle).
// MODE 0: bf16 store; 1: gelu->bf16; 4: out2 = h + val (final); 7: fp8 store.
// ---------------------------------------------------------------------------
template <int MODE, bool FUSED3>
__global__ __launch_bounds__(256) void gemm_kernel(const bf16_t* __restrict__ A,
                                                   const bf16_t* __restrict__ BT,
                                                   const void* b0, const void* b1, const void* b2,
                                                   long boff,
                                                   const int* f0, const int* f1, const int* f2,
                                                   void* __restrict__ Cout,
                                                   float* __restrict__ out2,
                                                   int N, int K) {
  const int fl0 = *f0;
  const int fl1 = FUSED3 ? *f1 : 0;
  const int fl2 = FUSED3 ? *f2 : 0;
  const int bm = blockIdx.y * 128;
  const int bn = blockIdx.x * 128;
  const int tid = threadIdx.x;
  const int lane = tid & 63;
  const int wid = tid >> 6;
  const int wr = wid >> 1, wc = wid & 1;
  const int lrow = lane & 15;
  const int lquad = lane >> 4;
  const int l8 = lane >> 3;
  const int u = lane & 7;

  __shared__ __align__(16) bf16_t As[128 * 64];
  __shared__ __align__(16) bf16_t Bs[128 * 64];

  const bf16_t* aptr[4];
  const bf16_t* bptr[4];
#pragma unroll
  for (int c = 0; c < 4; ++c) {
    int row = (wid * 4 + c) * 8 + l8;
    int kseg = (u ^ l8) << 3;
    aptr[c] = A + (size_t)(bm + row) * K + kseg;
    bptr[c] = BT + (size_t)(bn + row) * K + kseg;
  }

  f32x4 acc[4][4];
#pragma unroll
  for (int i = 0; i < 4; i++)
#pragma unroll
    for (int j = 0; j < 4; j++)
#pragma unroll
      for (int r = 0; r < 4; r++) acc[i][j][r] = 0.f;

  for (int k0 = 0; k0 < K; k0 += 64) {
#pragma unroll
    for (int c = 0; c < 4; ++c) {
      int chunk = wid * 4 + c;
      __builtin_amdgcn_global_load_lds(GLB_PTR(aptr[c] + k0), LDS_PTR(As + chunk * 512), 16, 0, 0);
      __builtin_amdgcn_global_load_lds(GLB_PTR(bptr[c] + k0), LDS_PTR(Bs + chunk * 512), 16, 0, 0);
    }
    __syncthreads();
#pragma unroll
    for (int ks = 0; ks < 2; ++ks) {
      bf16x8 a[4], b[4];
#pragma unroll
      for (int i = 0; i < 4; i++) {
        int pu = ((ks * 4 + lquad) ^ (lrow & 7)) * 8;
        a[i] = *(const bf16x8*)(&As[(wr * 64 + i * 16 + lrow) * 64 + pu]);
        b[i] = *(const bf16x8*)(&Bs[(wc * 64 + i * 16 + lrow) * 64 + pu]);
      }
#pragma unroll
      for (int i = 0; i < 4; i++)
#pragma unroll
        for (int j = 0; j < 4; j++)
          acc[i][j] = __builtin_amdgcn_mfma_f32_16x16x32_bf16(a[i], b[j], acc[i][j], 0, 0, 0);
    }
    __syncthreads();
  }

  // C/D layout: col = lane&15, row = (lane>>4)*4 + reg.
#pragma unroll
  for (int j = 0; j < 4; j++) {
    int n = bn + wc * 64 + j * 16 + lrow;
    float bv;
    if (FUSED3) {
      int seg = n >> 8;
      const void* bp = (seg == 0) ? b0 : ((seg == 1) ? b1 : b2);
      int fl = (seg == 0) ? fl0 : ((seg == 1) ? fl1 : fl2);
      bv = load_ext(bp, boff + (n & 255), fl);
    } else {
      bv = load_ext(b0, boff + n, fl0);
    }
#pragma unroll
    for (int i = 0; i < 4; i++) {
      int m0 = bm + wr * 64 + i * 16 + lquad * 4;
#pragma unroll
      for (int r = 0; r < 4; r++) {
        float val = acc[i][j][r] + bv;
        size_t idx = (size_t)(m0 + r) * N + n;
        if (MODE == 0) {
          ((bf16_t*)Cout)[idx] = (bf16_t)val;
        } else if (MODE == 1) {
          float gl = 0.5f * val * (1.f + erff(val * 0.7071067811865475f));
          ((bf16_t*)Cout)[idx] = (bf16_t)gl;
        } else if (MODE == 4) {
          out2[idx] = ((const float*)Cout)[idx] + val;
        } else if (MODE == 7) {
          unsigned pk = __builtin_amdgcn_cvt_pk_fp8_f32(val, val, 0u, false);
          ((unsigned char*)Cout)[idx] = (unsigned char)(pk & 0xFF);
        }
      }
    }
  }
}

// ---------------------------------------------------------------------------
// GEMM + fused LayerNorm. N fixed = 256; block = 64 rows x 256 cols.
// Writes h (fp32, += residual if RES) and xn = LN(h_new) (bf16).
// ---------------------------------------------------------------------------
template <bool RES>
__global__ __launch_bounds__(256) void gemm_ln(const bf16_t* __restrict__ A,
                                               const bf16_t* __restrict__ BT,
                                               const void* bias, long boff, const int* bfp,
                                               const void* g, long goff, const int* gfp,
                                               const void* bv2, long bvoff, const int* bvfp,
                                               float* __restrict__ h,
                                               bf16_t* __restrict__ xn,
                                               int K) {
  const int flb = *bfp, flg = *gfp, flbv = *bvfp;
  const int bm = blockIdx.y * 64;
  const int tid = threadIdx.x;
  const int lane = tid & 63;
  const int wid = tid >> 6;
  const int lrow = lane & 15;
  const int lquad = lane >> 4;
  const int l8 = lane >> 3;
  const int u = lane & 7;

  __shared__ __align__(16) bf16_t As[64 * 64];
  __shared__ __align__(16) bf16_t Bs[256 * 64];
  __shared__ float sums[64][4], sqs[64][4];
  __shared__ float mus[64], rss[64];

  const bf16_t* aptr[2];
#pragma unroll
  for (int c = 0; c < 2; ++c) {
    int chunk = wid * 2 + c;
    aptr[c] = A + (size_t)(bm + chunk * 8 + l8) * K + ((u ^ l8) << 3);
  }
  const bf16_t* bptr[8];
#pragma unroll
  for (int c = 0; c < 8; ++c) {
    int chunk = wid * 8 + c;
    bptr[c] = BT + (size_t)(chunk * 8 + l8) * K + ((u ^ l8) << 3);
  }

  f32x4 acc[4][4];
#pragma unroll
  for (int i = 0; i < 4; i++)
#pragma unroll
    for (int j = 0; j < 4; j++)
#pragma unroll
      for (int r = 0; r < 4; r++) acc[i][j][r] = 0.f;

  for (int k0 = 0; k0 < K; k0 += 64) {
#pragma unroll
    for (int c = 0; c < 2; ++c)
      __builtin_amdgcn_global_load_lds(GLB_PTR(aptr[c] + k0), LDS_PTR(As + (wid * 2 + c) * 512), 16, 0, 0);
#pragma unroll
    for (int c = 0; c < 8; ++c)
      __builtin_amdgcn_global_load_lds(GLB_PTR(bptr[c] + k0), LDS_PTR(Bs + (wid * 8 + c) * 512), 16, 0, 0);
    __syncthreads();
#pragma unroll
    for (int ks = 0; ks < 2; ++ks) {
      bf16x8 a[4], b[4];
      int pu = ((ks * 4 + lquad) ^ (lrow & 7)) * 8;
#pragma unroll
      for (int i = 0; i < 4; i++) {
        a[i] = *(const bf16x8*)(&As[(i * 16 + lrow) * 64 + pu]);
        b[i] = *(const bf16x8*)(&Bs[(wid * 64 + i * 16 + lrow) * 64 + pu]);
      }
#pragma unroll
      for (int i = 0; i < 4; i++)
#pragma unroll
        for (int j = 0; j < 4; j++)
          acc[i][j] = __builtin_amdgcn_mfma_f32_16x16x32_bf16(a[i], b[j], acc[i][j], 0, 0, 0);
    }
    __syncthreads();
  }

#pragma unroll
  for (int j = 0; j < 4; j++) {
    int n = wid * 64 + j * 16 + lrow;
    float bvv = load_ext(bias, boff + n, flb);
#pragma unroll
    for (int i = 0; i < 4; i++) {
      int rl = i * 16 + lquad * 4;
#pragma unroll
      for (int r = 0; r < 4; r++) {
        float v = acc[i][j][r] + bvv;
        size_t idx = (size_t)(bm + rl + r) * 256 + n;
        if (RES) v += h[idx];
        acc[i][j][r] = v;
        h[idx] = v;
      }
    }
  }
#pragma unroll
  for (int i = 0; i < 4; i++) {
#pragma unroll
    for (int r = 0; r < 4; r++) {
      float s = acc[i][0][r] + acc[i][1][r] + acc[i][2][r] + acc[i][3][r];
      float q = acc[i][0][r] * acc[i][0][r] + acc[i][1][r] * acc[i][1][r]
              + acc[i][2][r] * acc[i][2][r] + acc[i][3][r] * acc[i][3][r];
#pragma unroll
      for (int o = 1; o <= 8; o <<= 1) {
        s += __shfl_xor(s, o);
        q += __shfl_xor(q, o);
      }
      if (lrow == 0) {
        int row = i * 16 + lquad * 4 + r;
        sums[row][wid] = s;
        sqs[row][wid] = q;
      }
    }
  }
  __syncthreads();
  if (tid < 64) {
    float s = sums[tid][0] + sums[tid][1] + sums[tid][2] + sums[tid][3];
    float q = sqs[tid][0] + sqs[tid][1] + sqs[tid][2] + sqs[tid][3];
    float mu = s * (1.f / 256.f);
    float var = q * (1.f / 256.f) - mu * mu;
    mus[tid] = mu;
    rss[tid] = rsqrtf(var + 1e-5f);
  }
  __syncthreads();
#pragma unroll
  for (int j = 0; j < 4; j++) {
    int n = wid * 64 + j * 16 + lrow;
    float gv = load_ext(g, goff + n, flg);
    float bb = load_ext(bv2, bvoff + n, flbv);
#pragma unroll
    for (int i = 0; i < 4; i++) {
#pragma unroll
      for (int r = 0; r < 4; r++) {
        int row = i * 16 + lquad * 4 + r;
        float xv = (acc[i][j][r] - mus[row]) * rss[row] * gv + bb;
        xn[(size_t)(bm + row) * 256 + n] = (bf16_t)xv;
      }
    }
  }
}

// ---------------------------------------------------------------------------
extern "C" void kernel_launch(void* const* d_in, const int* in_sizes, int n_in,
                              void* d_out, int out_size, void* d_ws, size_t ws_size,
                              hipStream_t stream) {
  const void* ei = d_in[1];

  char* ws = (char*)d_ws;
  size_t o = 0;
  int* flags  = (int*)(ws + o);    o += 256;
  int* deg    = (int*)(ws + o);    o += (size_t)N_NODES * 4;
  int* cursor = (int*)(ws + o);    o += (size_t)N_NODES * 4;
  int* off    = (int*)(ws + o);    o += 131328;
  int* csr    = (int*)(ws + o);    o += (size_t)N_EDGES * 4;
  bf16_t* wT  = (bf16_t*)(ws + o); o += (size_t)1638400 * 2;
  float* h    = (float*)(ws + o);  o += (size_t)N_NODES * 256 * 4;   // 32 MB
  bf16_t* xn  = (bf16_t*)(ws + o); o += (size_t)N_NODES * 256 * 2;   // 16 MB
  bf16_t* big = (bf16_t*)(ws + o); o += (size_t)N_NODES * 1024 * 2;  // 64 MB arena
  bf16_t* xb = big;                          // converted x (dead before QKV)
  unsigned char* qkv8 = (unsigned char*)big; // [N,768] fp8 q|k|v
  bf16_t* ab = xn;                           // agg aliases xn
  bf16_t* ffnb = big;                        // [N,1024] bf16 (qkv8 dead then)

  // ---- D1: sniff + zero deg ----
  SniffArgs sa;
  for (int b = 0; b < 20; ++b) {
    sa.ptr[b] = d_in[b];
    sa.elems[b] = in_sizes[b];
    sa.kind[b] = (b == 1) ? 1 : 0;
  }
  prep1<<<52, 256, 0, stream>>>(sa, flags, deg);

  // ---- D2: convert x | transpose weights | degree count ----
  Prep2Args pa;
  pa.x = d_in[0]; pa.ei = ei; pa.xb = xb; pa.deg = deg;
  int tiles = 0, idx = 0;
  auto add = [&](int slot, long soff, bf16_t* dst, int K, int N) {
    pa.d[idx].src = d_in[slot]; pa.d[idx].soff = soff; pa.d[idx].dst = dst;
    pa.d[idx].K = K; pa.d[idx].N = N; pa.d[idx].tile0 = tiles;
    tiles += (K / 32) * (N / 32);
    ++idx;
  };
  bf16_t* wTin = wT;
  auto layer_base = [&](int l) { return wT + 65536 + (size_t)l * 786432; };
  add(2, 0, wTin, 256, 256);  // w_in
  for (int l = 0; l < 2; ++l) {
    bf16_t* base = layer_base(l);
    add(8,  (long)l * 65536,  base + 0,      256, 256);   // wq^T
    add(10, (long)l * 65536,  base + 65536,  256, 256);   // wk^T
    add(12, (long)l * 65536,  base + 131072, 256, 256);   // wv^T
    add(14, (long)l * 65536,  base + 196608, 256, 256);   // wo^T
    add(16, (long)l * 262144, base + 262144, 256, 1024);  // w1^T
    add(18, (long)l * 262144, base + 524288, 1024, 256);  // w2^T
  }
  prep2<<<11840, 256, 0, stream>>>(pa);  // 8192 + 1600 + 2048

  // ---- D3/D4: scan (off + cursor seed), scatter ----
  scan_offsets<<<1, 1024, 0, stream>>>(deg, off, cursor);
  scatter_edges<<<N_EDGES / 256, 256, 0, stream>>>(ei, nullptr, cursor, csr);

  // input proj + LN1(l0)
  gemm_ln<false><<<dim3(1, 512), 256, 0, stream>>>(
      xb, wTin, d_in[3], 0, flags + 3,
      d_in[4], 0, flags + 4, d_in[5], 0, flags + 5, h, xn, 256);

  for (int l = 0; l < 2; ++l) {
    bf16_t* base = layer_base(l);
    gemm_kernel<7, true><<<dim3(6, 256), 256, 0, stream>>>(
        xn, base, d_in[9], d_in[11], d_in[13], (long)l * 256,
        flags + 9, flags + 11, flags + 13, qkv8, nullptr, 768, 256);
    attn_k<<<N_NODES / 4, 256, 0, stream>>>(qkv8, off, csr, ab);
    gemm_ln<true><<<dim3(1, 512), 256, 0, stream>>>(
        ab, base + 196608, d_in[15], (long)l * 256, flags + 15,
        d_in[6], (long)l * 256, flags + 6, d_in[7], (long)l * 256, flags + 7,
        h, xn, 256);
    gemm_kernel<1, false><<<dim3(8, 256), 256, 0, stream>>>(
        xn, base + 262144, d_in[17], nullptr, nullptr, (long)l * 1024,
        flags + 17, flags + 17, flags + 17, ffnb, nullptr, 1024, 256);
    if (l == 0) {
      gemm_ln<true><<<dim3(1, 512), 256, 0, stream>>>(
          ffnb, base + 524288, d_in[19], 0, flags + 19,
          d_in[4], 256, flags + 4, d_in[5], 256, flags + 5, h, xn, 1024);
    } else {
      gemm_kernel<4, false><<<dim3(2, 256), 256, 0, stream>>>(
          ffnb, base + 524288, d_in[19], nullptr, nullptr, (long)l * 256,
          flags + 19, flags + 19, flags + 19, h, (float*)d_out, 256, 1024);
    }
  }
}